// Round 1
// baseline (2384.829 us; speedup 1.0000x reference)
//
#include <hip/hip_runtime.h>
#include <math.h>

#define NB 8
#define NC 128
#define HW 16384
#define NL 41

// ---------------------------------------------------------------------------
// K1: fused (r+d, r*sigmoid(d)) -> conv3x3 -> fuse, written to d_out.
// Block: 256 threads, tile = 32(x) x 64(y), 16 co per block, per-thread 16co x 8x.
// grid: cb(8) fastest, then xt(4), yt(2), b(8) = 512 blocks.
// ---------------------------------------------------------------------------
__global__ __launch_bounds__(256, 2)
void k_conv(const float* __restrict__ r, const float* __restrict__ d,
            const float* __restrict__ w, float* __restrict__ out)
{
    __shared__ float s_in[2][66][36];   // [add/mul][row -1..64][col -1..32, pad to 36]
    __shared__ float s_w[2][9][16];     // [tensor][tap][co]

    const int bid = blockIdx.x;
    const int cb = bid & 7;
    const int xt = (bid >> 3) & 3;
    const int yt = (bid >> 5) & 1;
    const int b  = bid >> 6;
    const int x0 = xt * 32, y0 = yt * 64;
    const int tid = (int)threadIdx.x;
    const int tx = tid & 3;          // 4 x-groups of 8 px
    const int ty = tid >> 2;         // 64 rows
    const int xb = tx * 8;

    float acc[16][8];
#pragma unroll
    for (int i = 0; i < 16; ++i)
#pragma unroll
        for (int j = 0; j < 8; ++j) acc[i][j] = 0.f;

    for (int ci = 0; ci < 128; ++ci) {
        __syncthreads();
        {
            const float* rp = r + ((size_t)(b * NC + ci)) * HW;
            const float* dp = d + ((size_t)(b * NC + ci)) * HW;
            for (int i = tid; i < 66 * 34; i += 256) {
                int ry = i / 34;
                int rx = i - ry * 34;
                int gy = y0 - 1 + ry;
                int gx = x0 - 1 + rx;
                float rv = 0.f, dv = 0.f;
                if ((unsigned)gy < 128u && (unsigned)gx < 128u) {
                    int gi = (gy << 7) | gx;
                    rv = rp[gi];
                    dv = dp[gi];
                }
                s_in[0][ry][rx] = rv + dv;
                s_in[1][ry][rx] = rv * (1.f / (1.f + __expf(-dv)));
            }
            // weights: conv_w[co][cin][ky][kx], cin = t*128 + ci
            for (int i = tid; i < 288; i += 256) {
                int t = i / 144;
                int rem = i - t * 144;
                int tap = rem >> 4;
                int co = rem & 15;
                s_w[t][tap][co] = w[((size_t)(cb * 16 + co) * 256 + t * 128 + ci) * 9 + tap];
            }
        }
        __syncthreads();

#pragma unroll
        for (int t = 0; t < 2; ++t) {
            float win[3][12];
#pragma unroll
            for (int k = 0; k < 3; ++k) {
                float4 v0 = *(const float4*)&s_in[t][ty + k][xb];
                float4 v1 = *(const float4*)&s_in[t][ty + k][xb + 4];
                float4 v2 = *(const float4*)&s_in[t][ty + k][xb + 8];
                win[k][0] = v0.x; win[k][1] = v0.y; win[k][2]  = v0.z; win[k][3]  = v0.w;
                win[k][4] = v1.x; win[k][5] = v1.y; win[k][6]  = v1.z; win[k][7]  = v1.w;
                win[k][8] = v2.x; win[k][9] = v2.y; win[k][10] = v2.z; win[k][11] = v2.w;
            }
#pragma unroll
            for (int ky = 0; ky < 3; ++ky) {
#pragma unroll
                for (int kx = 0; kx < 3; ++kx) {
                    const int tap = ky * 3 + kx;
                    float4 w0 = *(const float4*)&s_w[t][tap][0];
                    float4 w1 = *(const float4*)&s_w[t][tap][4];
                    float4 w2 = *(const float4*)&s_w[t][tap][8];
                    float4 w3 = *(const float4*)&s_w[t][tap][12];
                    float wv[16] = {w0.x, w0.y, w0.z, w0.w, w1.x, w1.y, w1.z, w1.w,
                                    w2.x, w2.y, w2.z, w2.w, w3.x, w3.y, w3.z, w3.w};
#pragma unroll
                    for (int co = 0; co < 16; ++co)
#pragma unroll
                        for (int xi = 0; xi < 8; ++xi)
                            acc[co][xi] += wv[co] * win[ky][xi + kx];
                }
            }
        }
    }

    const int y = y0 + ty;
#pragma unroll
    for (int co = 0; co < 16; ++co) {
        float4 v0 = make_float4(acc[co][0], acc[co][1], acc[co][2], acc[co][3]);
        float4 v1 = make_float4(acc[co][4], acc[co][5], acc[co][6], acc[co][7]);
        float* op = out + ((size_t)(b * NC + cb * 16 + co) * 128 + y) * 128 + x0 + xb;
        *(float4*)op = v0;
        *(float4*)(op + 4) = v1;
    }
}

// ---------------------------------------------------------------------------
// K2: segment partial sums for fuse (feat 0) and d (feat 1).
// 128 threads = one channel each; thread owns LDS bin column c -> no atomics.
// grid: 8 b x 16 chunks of 1024 px. partials[chunk][b][feat][l][c] in ws.
// ---------------------------------------------------------------------------
__global__ __launch_bounds__(128)
void k_seg(const float* __restrict__ fuse, const float* __restrict__ d,
           const int* __restrict__ label, float* __restrict__ partials)
{
    __shared__ float bin_f[NL][128];
    __shared__ float bin_d[NL][128];
    const int b = blockIdx.x & 7;
    const int chunk = blockIdx.x >> 3;
    const int c = (int)threadIdx.x;

#pragma unroll
    for (int l = 0; l < NL; ++l) { bin_f[l][c] = 0.f; bin_d[l][c] = 0.f; }

    const float* fp = fuse + ((size_t)(b * NC + c)) * HW;
    const float* dp = d + ((size_t)(b * NC + c)) * HW;
    const int* lp = label + (size_t)b * 512 * 512;
    const int p0 = chunk * 1024;

    for (int i = 0; i < 1024; i += 4) {
        int p = p0 + i;
        int y = p >> 7, x = p & 127;
        const int* lrow = lp + (y * 4) * 512 + x * 4;   // nearest = stride-4 sample
        int l0 = lrow[0], l1 = lrow[4], l2 = lrow[8], l3 = lrow[12];
        float4 fv = *(const float4*)&fp[p];
        float4 dv = *(const float4*)&dp[p];
        bin_f[l0][c] += fv.x; bin_f[l1][c] += fv.y; bin_f[l2][c] += fv.z; bin_f[l3][c] += fv.w;
        bin_d[l0][c] += dv.x; bin_d[l1][c] += dv.y; bin_d[l2][c] += dv.z; bin_d[l3][c] += dv.w;
    }

    float* pf = partials + ((size_t)((chunk * 8 + b) * 2 + 0) * NL) * 128;
    float* pd = partials + ((size_t)((chunk * 8 + b) * 2 + 1) * NL) * 128;
#pragma unroll
    for (int l = 0; l < NL; ++l) {
        pf[l * 128 + c] = bin_f[l][c];
        pd[l * 128 + c] = bin_d[l][c];
    }
}

// ---------------------------------------------------------------------------
// K3: per (b, feat): label histogram, reduce partials, mean/base select,
// L2-normalize over classes, sum, 2-layer SE MLP, sigmoid -> gates.
// grid 16 = (b,feat), 128 threads (thread = channel c).
// ---------------------------------------------------------------------------
__global__ __launch_bounds__(128)
void k_gates(const float* __restrict__ partials, const int* __restrict__ label,
             const float* __restrict__ base_f, const float* __restrict__ base_d,
             const float* __restrict__ f_w1, const float* __restrict__ f_w2,
             const float* __restrict__ d_w1, const float* __restrict__ d_w2,
             float* __restrict__ gates)
{
    __shared__ int hist[NL];
    __shared__ float sv[128];
    __shared__ float h1[8];
    const int b = blockIdx.x >> 1;
    const int feat = blockIdx.x & 1;
    const int c = (int)threadIdx.x;

    if (c < NL) hist[c] = 0;
    __syncthreads();
    const int* lp = label + (size_t)b * 512 * 512;
    for (int i = c; i < HW; i += 128) {
        int y = i >> 7, x = i & 127;
        atomicAdd(&hist[lp[(y * 4) * 512 + x * 4]], 1);
    }
    __syncthreads();

    const float* base = feat ? base_d : base_f;
    float suma = 0.f, sumsq = 0.f;
    for (int l = 0; l < NL; ++l) {
        float s = 0.f;
#pragma unroll
        for (int ch = 0; ch < 16; ++ch)
            s += partials[((size_t)((ch * 8 + b) * 2 + feat) * NL + l) * 128 + c];
        int cnt = hist[l];
        float att = (cnt > 0) ? (s / (float)cnt) : base[(b * NL + l) * 128 + c];
        suma += att;
        sumsq += att * att;
    }
    sv[c] = suma / fmaxf(sqrtf(sumsq), 1e-12f);
    __syncthreads();

    const float* w1 = feat ? d_w1 : f_w1;
    const float* w2 = feat ? d_w2 : f_w2;
    if (c < 8) {
        float h = 0.f;
        for (int k = 0; k < 128; ++k) h += w1[c * 128 + k] * sv[k];
        h1[c] = fmaxf(h, 0.f);
    }
    __syncthreads();

    float g = 0.f;
#pragma unroll
    for (int o = 0; o < 8; ++o) g += w2[c * 8 + o] * h1[o];
    gates[feat * 1024 + b * 128 + c] = 1.f / (1.f + expf(-g));
}

// ---------------------------------------------------------------------------
// K4: out = fuse * g_f + d * g_d (fuse read in-place from d_out).
// ---------------------------------------------------------------------------
__global__ __launch_bounds__(256)
void k_final(const float* __restrict__ d, const float* __restrict__ gates,
             float* out)
{
    size_t t4 = (size_t)blockIdx.x * 256 + threadIdx.x;
    size_t basei = t4 * 4;
    int bc = (int)(basei >> 14);           // b*128 + c (wave-uniform -> broadcast)
    float gf = gates[bc];
    float gd = gates[1024 + bc];
    float4 f = *(const float4*)(out + basei);
    float4 dv = *(const float4*)(d + basei);
    float4 o;
    o.x = f.x * gf + dv.x * gd;
    o.y = f.y * gf + dv.y * gd;
    o.z = f.z * gf + dv.z * gd;
    o.w = f.w * gf + dv.w * gd;
    *(float4*)(out + basei) = o;
}

extern "C" void kernel_launch(void* const* d_in, const int* in_sizes, int n_in,
                              void* d_out, int out_size, void* d_ws, size_t ws_size,
                              hipStream_t stream)
{
    (void)in_sizes; (void)n_in; (void)out_size; (void)ws_size;
    const float* r      = (const float*)d_in[0];
    const float* d      = (const float*)d_in[1];
    const int*   label  = (const int*)d_in[2];
    const float* conv_w = (const float*)d_in[3];
    const float* f_w1   = (const float*)d_in[4];
    const float* f_w2   = (const float*)d_in[5];
    const float* d_w1   = (const float*)d_in[6];
    const float* d_w2   = (const float*)d_in[7];
    const float* base_f = (const float*)d_in[8];
    const float* base_d = (const float*)d_in[9];
    float* out = (float*)d_out;

    float* partials = (float*)d_ws;                     // 16*8*2*41*128 f = 5.25 MB
    float* gates = partials + 16 * 8 * 2 * NL * 128;    // 2*8*128 f

    hipLaunchKernelGGL(k_conv, dim3(512), dim3(256), 0, stream, r, d, conv_w, out);
    hipLaunchKernelGGL(k_seg, dim3(128), dim3(128), 0, stream, out, d, label, partials);
    hipLaunchKernelGGL(k_gates, dim3(16), dim3(128), 0, stream, partials, label,
                       base_f, base_d, f_w1, f_w2, d_w1, d_w2, gates);
    hipLaunchKernelGGL(k_final, dim3(16384), dim3(256), 0, stream, d, gates, out);
}

// Round 2
// 463.061 us; speedup vs baseline: 5.1501x; 5.1501x over previous
//
#include <hip/hip_runtime.h>
#include <math.h>

typedef unsigned short u16;
typedef unsigned int u32;
typedef __bf16 bf16x8 __attribute__((ext_vector_type(8)));
typedef float f32x4 __attribute__((ext_vector_type(4)));

#define NL 41
#define HW 16384

// ws layout (bytes)
#define NHWC_OFF   0            // 8*16384*256 bf16 = 67,108,864 B
#define WA_OFF     67108864     // 72*8*64*8 bf16   =    589,824 B
#define PART_OFF   67698688     // 32*8*2*41*128 f32 = 10,747,904 B
#define GATES_OFF  78446592     // 2*8*128 f32

__device__ __forceinline__ u16 f2bf(float f) {
    u32 u = __builtin_bit_cast(u32, f);
    u = (u + 0x7FFFu + ((u >> 16) & 1u)) >> 16;
    return (u16)u;
}

__device__ __forceinline__ void glds16(const void* g, void* l) {
    __builtin_amdgcn_global_load_lds(
        (const __attribute__((address_space(1))) void*)g,
        (__attribute__((address_space(3))) void*)l, 16, 0, 0);
}

// ---------------------------------------------------------------------------
// K0: fused add/mul -> bf16 NHWC [b][p][c'] (c' 0..127 = r+d, 128..255 = r*sig(d)).
// LDS transpose; c'-blocks XOR-swizzled by (px>>4)&3 to dodge write-bank conflicts.
// grid = 8b * 128 px-groups of 128 px, 256 thr.
// ---------------------------------------------------------------------------
__global__ __launch_bounds__(256, 2)
void k_prep(const float* __restrict__ r, const float* __restrict__ d,
            u16* __restrict__ nhwc)
{
    __shared__ u16 s[128 * 256];            // 64 KB, [px][c'sw]
    const int bid = (int)blockIdx.x;
    const int b = bid >> 7;
    const int p0 = (bid & 127) * 128;
    const int tid = (int)threadIdx.x;
    const int cl = tid >> 3;                // 0..31
    const int q = tid & 7;
    const int swz = (q & 3) << 3;           // XOR on c' bits 3..4

#pragma unroll
    for (int cc = 0; cc < 4; ++cc) {
        int c = cc * 32 + cl;
        const float* rp = r + ((size_t)(b * 128 + c)) * HW + p0;
        const float* dp = d + ((size_t)(b * 128 + c)) * HW + p0;
#pragma unroll
        for (int k = 0; k < 4; ++k) {
            int px = q * 16 + k * 4;
            float4 rv = *(const float4*)(rp + px);
            float4 dv = *(const float4*)(dp + px);
            float ra[4] = {rv.x, rv.y, rv.z, rv.w};
            float da[4] = {dv.x, dv.y, dv.z, dv.w};
#pragma unroll
            for (int i = 0; i < 4; ++i) {
                float ad = ra[i] + da[i];
                float ml = ra[i] / (1.f + __expf(-da[i]));
                int pxi = px + i;
                s[pxi * 256 + (c ^ swz)] = f2bf(ad);
                s[pxi * 256 + ((128 + c) ^ swz)] = f2bf(ml);
            }
        }
    }
    __syncthreads();
    const f32x4* sf = (const f32x4*)s;
    f32x4* dst = (f32x4*)(nhwc + ((size_t)b * HW + p0) * 256);
#pragma unroll
    for (int k = 0; k < 16; ++k) {
        int fi = k * 256 + tid;             // float4 index, 4096 total
        int px = fi >> 5, blk = fi & 31;
        int sw = (px >> 4) & 3;
        dst[px * 32 + (blk ^ sw)] = sf[fi];
    }
}

// ---------------------------------------------------------------------------
// K0b: weight repack -> Wa[kt][ct][lane][8] bf16, kt = chunk*9+tap, lane: co=l&15,
// cin = chunk*32 + (l>>4)*8 + j. A-frag load becomes one coalesced 16B/lane read.
// ---------------------------------------------------------------------------
__global__ __launch_bounds__(64)
void k_wpack(const float* __restrict__ w, u16* __restrict__ wa)
{
    const int bid = (int)blockIdx.x;        // kt*8 + ct, 576 blocks
    const int l = (int)threadIdx.x;
    const int kt = bid >> 3, ct = bid & 7;
    const int chunk = kt / 9, tap = kt - chunk * 9;
    const int co = ct * 16 + (l & 15);
    const int cin0 = chunk * 32 + (l >> 4) * 8;
    u16 tmp[8];
#pragma unroll
    for (int j = 0; j < 8; ++j)
        tmp[j] = f2bf(w[((size_t)co * 256 + cin0 + j) * 9 + tap]);
    *(f32x4*)&wa[((size_t)bid * 64 + l) * 8] = *(f32x4*)tmp;
}

// ---------------------------------------------------------------------------
// K1: conv3x3 as 9-tap implicit GEMM, bf16 MFMA 16x16x32.
// Block: 128 co x 256 px (2 rows); 4 waves of 64co x 128px (4 ct x 8 p frags).
// K-loop: 8 chunks of 32 c'; LDS [row 0..3][xslot 0..129][ci 0..31] bf16, staged
// via global_load_lds(16B); border halo pre-zeroed once (masked lanes skip).
// grid = 8b * 64 row-pairs = 512 blocks (2/CU).
// ---------------------------------------------------------------------------
__global__ __launch_bounds__(256, 2)
void k_conv(const u16* __restrict__ nhwc, const u16* __restrict__ wa,
            float* __restrict__ out)
{
    __shared__ u16 s_in[4 * 130 * 32];      // 33280 B
    const int tid = (int)threadIdx.x;
    const int bid = (int)blockIdx.x;
    const int y0 = (bid & 63) * 2;
    const int b = bid >> 6;
    const int l = tid & 63;
    const int wv = tid >> 6;
    const int wr = wv & 1;                  // image row within pair
    const int wc = wv >> 1;                 // co half
    const int l15 = l & 15;
    const int l16 = l >> 4;

    {   // zero border-halo slots (never written by staging; persists all chunks)
        f32x4 zz = {0.f, 0.f, 0.f, 0.f};
        for (int s = tid; s < 2080; s += 256) {
            int row = s / 520;
            int rem = s - row * 520;
            int gy = y0 - 1 + row;
            int gx = (rem >> 2) - 1;
            if ((unsigned)gy >= 128u || (unsigned)gx >= 128u)
                *(f32x4*)&s_in[s * 8] = zz;
        }
    }

    f32x4 acc[4][8];
#pragma unroll
    for (int i = 0; i < 4; ++i)
#pragma unroll
        for (int j = 0; j < 8; ++j) {
            f32x4 zz = {0.f, 0.f, 0.f, 0.f};
            acc[i][j] = zz;
        }

    const u16* src_b = nhwc + (size_t)b * HW * 256;
    const f32x4* wa4 = (const f32x4*)wa;

#pragma unroll 1
    for (int chunk = 0; chunk < 8; ++chunk) {
        __syncthreads();
        // stage 2080 16B slots: slot = row*520 + xslot*4 + ci8
#pragma unroll
        for (int it = 0; it < 9; ++it) {
            int s = it * 256 + tid;
            if (s < 2080) {
                int row = s / 520;
                int rem = s - row * 520;
                int xslot = rem >> 2;
                int ci8 = rem & 3;
                int gy = y0 - 1 + row;
                int gx = xslot - 1;
                if ((unsigned)gy < 128u && (unsigned)gx < 128u) {
                    const u16* g = src_b + ((size_t)(gy * 128 + gx)) * 256
                                 + chunk * 32 + ci8 * 8;
                    u16* lb = &s_in[(it * 256 + (tid & 192)) * 8];
                    glds16(g, lb);
                }
            }
        }
        // prefetch tap-0 A frags; barrier's vmcnt(0) drain completes them free
        f32x4 aN[4];
        {
            int kt8 = chunk * 9 * 8;
#pragma unroll
            for (int i = 0; i < 4; ++i)
                aN[i] = wa4[(kt8 + wc * 4 + i) * 64 + l];
        }
        __syncthreads();

#pragma unroll
        for (int tap = 0; tap < 9; ++tap) {
            f32x4 aC[4];
#pragma unroll
            for (int i = 0; i < 4; ++i) aC[i] = aN[i];
            if (tap < 8) {
                int kt8 = (chunk * 9 + tap + 1) * 8;
#pragma unroll
                for (int i = 0; i < 4; ++i)
                    aN[i] = wa4[(kt8 + wc * 4 + i) * 64 + l];
            }
            const int rowi = wr + tap / 3;      // wr + dy + 1
            const int dxo = tap % 3;            // dx + 1
            f32x4 bf[8];
#pragma unroll
            for (int p = 0; p < 8; ++p) {
                int e = (rowi * 130 + p * 16 + l15 + dxo) * 32 + l16 * 8;
                bf[p] = *(const f32x4*)&s_in[e];
            }
#pragma unroll
            for (int ct = 0; ct < 4; ++ct) {
                bf16x8 av = __builtin_bit_cast(bf16x8, aC[ct]);
#pragma unroll
                for (int p = 0; p < 8; ++p)
                    acc[ct][p] = __builtin_amdgcn_mfma_f32_16x16x32_bf16(
                        av, __builtin_bit_cast(bf16x8, bf[p]), acc[ct][p], 0, 0, 0);
            }
        }
    }

    // epilogue: D col = px = l&15, row = co = (l>>4)*4 + reg
    const int y = y0 + wr;
    float* outb = out + (size_t)b * 128 * HW + (size_t)y * 128;
#pragma unroll
    for (int ct = 0; ct < 4; ++ct)
#pragma unroll
        for (int p = 0; p < 8; ++p) {
            int x = p * 16 + l15;
#pragma unroll
            for (int rr = 0; rr < 4; ++rr) {
                int co = wc * 64 + ct * 16 + l16 * 4 + rr;
                outb[(size_t)co * HW + x] = acc[ct][p][rr];
            }
        }
}

// ---------------------------------------------------------------------------
// K2: segment partial sums (fuse from d_out, d). 256 blocks = 8b x 32 chunks
// of 512 px. Thread owns channel column -> conflict-free LDS bins, no atomics.
// ---------------------------------------------------------------------------
__global__ __launch_bounds__(128)
void k_seg(const float* __restrict__ fuse, const float* __restrict__ d,
           const int* __restrict__ label, float* __restrict__ partials)
{
    __shared__ float bin_f[NL][128];
    __shared__ float bin_d[NL][128];
    const int b = (int)blockIdx.x & 7;
    const int chunk = (int)blockIdx.x >> 3;
    const int c = (int)threadIdx.x;

#pragma unroll
    for (int i = 0; i < NL; ++i) { bin_f[i][c] = 0.f; bin_d[i][c] = 0.f; }

    const float* fp = fuse + ((size_t)(b * 128 + c)) * HW;
    const float* dp = d + ((size_t)(b * 128 + c)) * HW;
    const int* lp = label + (size_t)b * 512 * 512;
    const int p0 = chunk * 512;

    for (int i = 0; i < 512; i += 4) {
        int p = p0 + i;
        int y = p >> 7, x = p & 127;
        const int* lrow = lp + (y * 4) * 512 + x * 4;
        int l0 = lrow[0], l1 = lrow[4], l2 = lrow[8], l3 = lrow[12];
        float4 fv = *(const float4*)&fp[p];
        float4 dv = *(const float4*)&dp[p];
        bin_f[l0][c] += fv.x; bin_f[l1][c] += fv.y; bin_f[l2][c] += fv.z; bin_f[l3][c] += fv.w;
        bin_d[l0][c] += dv.x; bin_d[l1][c] += dv.y; bin_d[l2][c] += dv.z; bin_d[l3][c] += dv.w;
    }

    float* pf = partials + (size_t)((chunk * 8 + b) * 2 + 0) * NL * 128;
    float* pd = partials + (size_t)((chunk * 8 + b) * 2 + 1) * NL * 128;
#pragma unroll
    for (int i = 0; i < NL; ++i) {
        pf[i * 128 + c] = bin_f[i][c];
        pd[i * 128 + c] = bin_d[i][c];
    }
}

// ---------------------------------------------------------------------------
// K3: histogram + reduce + mean/base + L2-normalize over classes + SE MLP.
// ---------------------------------------------------------------------------
__global__ __launch_bounds__(128)
void k_gates(const float* __restrict__ partials, const int* __restrict__ label,
             const float* __restrict__ base_f, const float* __restrict__ base_d,
             const float* __restrict__ f_w1, const float* __restrict__ f_w2,
             const float* __restrict__ d_w1, const float* __restrict__ d_w2,
             float* __restrict__ gates)
{
    __shared__ int hist[NL];
    __shared__ float sv[128];
    __shared__ float h1[8];
    const int b = (int)blockIdx.x >> 1;
    const int feat = (int)blockIdx.x & 1;
    const int c = (int)threadIdx.x;

    if (c < NL) hist[c] = 0;
    __syncthreads();
    const int* lp = label + (size_t)b * 512 * 512;
    for (int i = c; i < HW; i += 128) {
        int y = i >> 7, x = i & 127;
        atomicAdd(&hist[lp[(y * 4) * 512 + x * 4]], 1);
    }
    __syncthreads();

    const float* base = feat ? base_d : base_f;
    float suma = 0.f, sumsq = 0.f;
    for (int lcls = 0; lcls < NL; ++lcls) {
        float s = 0.f;
#pragma unroll
        for (int ch = 0; ch < 32; ++ch)
            s += partials[(size_t)(((ch * 8 + b) * 2 + feat) * NL + lcls) * 128 + c];
        int cnt = hist[lcls];
        float att = (cnt > 0) ? (s / (float)cnt) : base[(b * NL + lcls) * 128 + c];
        suma += att;
        sumsq += att * att;
    }
    sv[c] = suma / fmaxf(sqrtf(sumsq), 1e-12f);
    __syncthreads();

    const float* w1 = feat ? d_w1 : f_w1;
    const float* w2 = feat ? d_w2 : f_w2;
    if (c < 8) {
        float h = 0.f;
        for (int k = 0; k < 128; ++k) h += w1[c * 128 + k] * sv[k];
        h1[c] = fmaxf(h, 0.f);
    }
    __syncthreads();

    float g = 0.f;
#pragma unroll
    for (int o = 0; o < 8; ++o) g += w2[c * 8 + o] * h1[o];
    gates[feat * 1024 + b * 128 + c] = 1.f / (1.f + expf(-g));
}

// ---------------------------------------------------------------------------
// K4: out = fuse * g_f + d * g_d (fuse in-place in d_out).
// ---------------------------------------------------------------------------
__global__ __launch_bounds__(256)
void k_final(const float* __restrict__ d, const float* __restrict__ gates,
             float* out)
{
    size_t t4 = (size_t)blockIdx.x * 256 + threadIdx.x;
    size_t basei = t4 * 4;
    int bc = (int)(basei >> 14);
    float gf = gates[bc];
    float gd = gates[1024 + bc];
    float4 f = *(const float4*)(out + basei);
    float4 dv = *(const float4*)(d + basei);
    float4 o;
    o.x = f.x * gf + dv.x * gd;
    o.y = f.y * gf + dv.y * gd;
    o.z = f.z * gf + dv.z * gd;
    o.w = f.w * gf + dv.w * gd;
    *(float4*)(out + basei) = o;
}

extern "C" void kernel_launch(void* const* d_in, const int* in_sizes, int n_in,
                              void* d_out, int out_size, void* d_ws, size_t ws_size,
                              hipStream_t stream)
{
    (void)in_sizes; (void)n_in; (void)out_size; (void)ws_size;
    const float* r      = (const float*)d_in[0];
    const float* d      = (const float*)d_in[1];
    const int*   label  = (const int*)d_in[2];
    const float* conv_w = (const float*)d_in[3];
    const float* f_w1   = (const float*)d_in[4];
    const float* f_w2   = (const float*)d_in[5];
    const float* d_w1   = (const float*)d_in[6];
    const float* d_w2   = (const float*)d_in[7];
    const float* base_f = (const float*)d_in[8];
    const float* base_d = (const float*)d_in[9];
    float* out = (float*)d_out;

    char* ws = (char*)d_ws;
    u16* nhwc      = (u16*)(ws + NHWC_OFF);
    u16* wa        = (u16*)(ws + WA_OFF);
    float* partials = (float*)(ws + PART_OFF);
    float* gates    = (float*)(ws + GATES_OFF);

    hipLaunchKernelGGL(k_prep, dim3(1024), dim3(256), 0, stream, r, d, nhwc);
    hipLaunchKernelGGL(k_wpack, dim3(576), dim3(64), 0, stream, conv_w, wa);
    hipLaunchKernelGGL(k_conv, dim3(512), dim3(256), 0, stream, nhwc, wa, out);
    hipLaunchKernelGGL(k_seg, dim3(256), dim3(128), 0, stream, out, d, label, partials);
    hipLaunchKernelGGL(k_gates, dim3(16), dim3(128), 0, stream, partials, label,
                       base_f, base_d, f_w1, f_w2, d_w1, d_w2, gates);
    hipLaunchKernelGGL(k_final, dim3(16384), dim3(256), 0, stream, d, gates, out);
}